// Round 15
// baseline (357.548 us; speedup 1.0000x reference)
//
#include <hip/hip_runtime.h>

typedef __bf16 bf16x8 __attribute__((ext_vector_type(8)));
typedef float  f32x4  __attribute__((ext_vector_type(4)));
typedef int    i32x4  __attribute__((ext_vector_type(4)));
typedef char   c16    __attribute__((ext_vector_type(16)));

constexpr int M_ROWS = 65536;
constexpr int N_COLS = 2048;
constexpr int K_DIM  = 512;
constexpr int NKQ    = 8;              // kt-tiles of K=64
constexpr int MBQ    = 512;            // 128-row tiles
constexpr int NBQ    = 16;             // 128-col WQ blocks

// ws layout: sX 65536 f | sW 2048 f | AQ 64 MiB | WQ 2 MiB
constexpr size_t AQ_OFF  = (65536 + 2048) * 4;
constexpr size_t AQ_SZ   = (size_t)MBQ * NKQ * 16384;
constexpr size_t WQ_OFF  = AQ_OFF + AQ_SZ;
constexpr size_t WQ_SZ   = (size_t)NBQ * NKQ * 16384;
constexpr size_t NEEDQ   = WQ_OFF + WQ_SZ;

__device__ __forceinline__ unsigned short f2bf(float f){
  unsigned int u = __float_as_uint(f);
  u += 0x7FFFu + ((u >> 16) & 1u);
  return (unsigned short)(u >> 16);
}
__device__ __forceinline__ float bf2f(unsigned short h){
  return __uint_as_float(((unsigned int)h) << 16);
}
__device__ __forceinline__ void split4(const float4& v, ushort4& h, ushort4& l){
  h.x = f2bf(v.x); l.x = f2bf(v.x - bf2f(h.x));
  h.y = f2bf(v.y); l.y = f2bf(v.y - bf2f(h.y));
  h.z = f2bf(v.z); l.z = f2bf(v.z - bf2f(h.z));
  h.w = f2bf(v.w); l.w = f2bf(v.w - bf2f(h.w));
}

__device__ __forceinline__ void gl_lds16(const void* g, void* l){
  __builtin_amdgcn_global_load_lds(
      (const __attribute__((address_space(1))) unsigned int*)g,
      (__attribute__((address_space(3))) unsigned int*)l, 16, 0, 0);
}

constexpr float INV2PI = 0.15915494309189535f;
__device__ __forceinline__ float cos_scaled(float v){
  float rev = v * INV2PI;
  rev -= floorf(rev);
  return 0.03125f * __builtin_amdgcn_cosf(rev);
}

__device__ __forceinline__ void q2(float x, float inv, char& o1, char& o2){
  float t1 = x * inv;
  float r1 = rintf(t1);
  float r2 = fminf(rintf((t1 - r1) * 256.0f), 127.0f);
  o1 = (char)(int)r1;
  o2 = (char)(int)r2;
}

// ============ prepass 1: X -> AQ (fused rowmax + 2-split i8, frag-linear) ===
__global__ void pack_xq(const float* __restrict__ X, char* __restrict__ AQ,
                        float* __restrict__ sXo){
  const int bid = blockIdx.x;          // 2048 blocks x 32 rows
  const int t = threadIdx.x;
  const int rl = t >> 3, seg = t & 7;  // seg == kt
  const int grow = bid * 32 + rl;
  const float* src = X + (size_t)grow * K_DIM + seg * 64;
  f32x4 v[16];
  #pragma unroll
  for (int i = 0; i < 16; ++i)
    v[i] = __builtin_nontemporal_load(reinterpret_cast<const f32x4*>(src) + i);
  float m = 0.f;
  #pragma unroll
  for (int i = 0; i < 16; ++i)
    m = fmaxf(m, fmaxf(fmaxf(fabsf(v[i].x), fabsf(v[i].y)),
                       fmaxf(fabsf(v[i].z), fabsf(v[i].w))));
  m = fmaxf(m, __shfl_xor(m, 1));
  m = fmaxf(m, __shfl_xor(m, 2));
  m = fmaxf(m, __shfl_xor(m, 4));
  m = fmaxf(m, 1e-10f);
  if (seg == 0) sXo[grow] = m * (1.0f / 127.0f);
  const float inv = 127.0f / m;

  const int mb = bid >> 2;
  const int rowt = (bid & 3) * 32 + rl;
  const int i_ = rowt >> 4, r_ = rowt & 15;
  char* tb = AQ + (size_t)(mb * NKQ + seg) * 16384;
  #pragma unroll
  for (int q = 0; q < 4; ++q){
    c16 o1, o2;
    #pragma unroll
    for (int u = 0; u < 4; ++u){
      f32x4 xv = v[q * 4 + u];
      #pragma unroll
      for (int w = 0; w < 4; ++w){
        char a, b; q2(xv[w], inv, a, b);
        o1[u * 4 + w] = a; o2[u * 4 + w] = b;
      }
    }
    int c = i_ * 64 + q * 16 + r_;
    *reinterpret_cast<c16*>(tb + c * 16)        = o1;
    *reinterpret_cast<c16*>(tb + 8192 + c * 16) = o2;
  }
}

// ============ prepass 2 (fused): per-col max + W -> WQ pack =================
// One block per nb (16 blocks x 256 thr). Phase A: colmax over full K ->
// sWl (LDS) + sW (global). Phase B: 8x {transpose slab, quantize, col-perm}.
// All quantize expressions bit-identical to the proven split kernels.
__global__ void prep_w(const float* __restrict__ W, float* __restrict__ sWo,
                       char* __restrict__ WQ){
  __shared__ float tf[64][132];
  __shared__ float sWl[128];
  const int nb = blockIdx.x, t = threadIdx.x;
  const int n0 = nb * 128;
  {
    int c = t & 127, kh = t >> 7;        // 2 k-halves x 128 cols
    float m = 0.f;
    for (int k = kh * 256; k < kh * 256 + 256; ++k)
      m = fmaxf(m, fabsf(W[(size_t)k * N_COLS + n0 + c]));
    float* red = reinterpret_cast<float*>(tf);
    red[kh * 128 + c] = m;
    __syncthreads();
    if (t < 128){
      float mm = fmaxf(fmaxf(red[t], red[128 + t]), 1e-10f) * (1.0f / 127.0f);
      sWl[t] = mm;
      sWo[n0 + t] = mm;
    }
    __syncthreads();
  }
  const int kr = t >> 2, nq = t & 3;
  #pragma unroll 1
  for (int kt = 0; kt < NKQ; ++kt){
    #pragma unroll
    for (int it = 0; it < 8; ++it){
      f32x4 v4 = *reinterpret_cast<const f32x4*>(
          W + (size_t)(kt * 64 + kr) * N_COLS + n0 + nq * 32 + it * 4);
      *reinterpret_cast<f32x4*>(&tf[kr][nq * 32 + it * 4]) = v4;
    }
    __syncthreads();
    char* tb = WQ + (size_t)(nb * NKQ + kt) * 16384;
    #pragma unroll
    for (int cc = 0; cc < 2; ++cc){
      int c = t + cc * 256;
      int jj = c >> 6, q = (c >> 4) & 3, fc = c & 15;
      int col_local = (jj >> 2) * 64 + fc * 4 + (jj & 3);
      float inv = 1.0f / sWl[col_local];
      c16 o1, o2;
      #pragma unroll
      for (int e = 0; e < 16; ++e){
        char a, b; q2(tf[q * 16 + e][col_local], inv, a, b);
        o1[e] = a; o2[e] = b;
      }
      *reinterpret_cast<c16*>(tb + c * 16)        = o1;
      *reinterpret_cast<c16*>(tb + 8192 + c * 16) = o2;
    }
    __syncthreads();
  }
}

// ============ main GEMM: 128x64 tiles, counted-vmcnt barrier ================
// 4 waves x (32 rows x 64 cols). A: per-lane global (reg-dbuf). B: LDS dbuf
// 2 x 8 KB. Per step, pinned issue order: 2 B-gl_lds -> 4 A-loads; end-of-
// step wait = vmcnt(4) (B landed, A floats to use) + RAW s_barrier.
#define MFMAI(a,b,c) __builtin_amdgcn_mfma_i32_16x16x64_i8(a,b,c,0,0,0)
#define DRAIN_BAR() { asm volatile("s_waitcnt vmcnt(0)" ::: "memory"); \
                      __builtin_amdgcn_sched_barrier(0); __syncthreads(); }
#define CNT_BAR4() { asm volatile("s_waitcnt vmcnt(4)" ::: "memory"); \
                     __builtin_amdgcn_s_barrier(); \
                     __builtin_amdgcn_sched_barrier(0); }

__launch_bounds__(256, 4)
__global__ void rbf_gemm_i8(const char* __restrict__ AQ, const char* __restrict__ WQ,
                            const float* __restrict__ sX, const float* __restrict__ sW,
                            const float* __restrict__ bvec, float* __restrict__ out){
  __shared__ __align__(16) char smem[2 * 8192];   // 16 KB: 2 slots x [p1 4K|p2 4K]

  int orig = blockIdx.x;                          // 16384, % 8 == 0
  int wgid = (orig & 7) * 2048 + (orig >> 3);     // bijective XCD swizzle;
  int mb = wgid >> 5, nb2 = wgid & 31;            // 32 consecutive share one AQ tile
  int nb = nb2 >> 1, wn2 = nb2 & 1;

  int tid = threadIdx.x, lane = tid & 63, wid = tid >> 6;  // wave = 32-row group
  int r = lane & 15, g = lane >> 4;

  const char* abase = AQ + (size_t)mb * NKQ * 16384;
  const char* bbase = WQ + ((size_t)nb * NKQ) * 16384 + wn2 * 4096;
  const int soff = wid * 1024 + lane * 16;        // per-lane global src offset
  const int doff = wid * 1024;                    // WAVE-UNIFORM LDS dest offset

  int aoffs[2];
  #pragma unroll
  for (int i = 0; i < 2; ++i) aoffs[i] = (wid * 2 + i) * 1024 + lane * 16;
  int boffs[4];
  #pragma unroll
  for (int j = 0; j < 4; ++j) boffs[j] = j * 1024 + lane * 16;

  i32x4 accm[2][4], accc[2][4];
  #pragma unroll
  for (int i = 0; i < 2; ++i)
    #pragma unroll
    for (int j = 0; j < 4; ++j){
      accm[i][j] = (i32x4){0,0,0,0};
      accc[i][j] = (i32x4){0,0,0,0};
    }

  i32x4 a1A[2], a2A[2], a1B[2], a2B[2];

  // prologue: A[0] -> set A, B[0] halves -> buf0 (full drain once)
  #pragma unroll
  for (int i = 0; i < 2; ++i){
    a1A[i] = *reinterpret_cast<const i32x4*>(abase + aoffs[i]);
    a2A[i] = *reinterpret_cast<const i32x4*>(abase + 8192 + aoffs[i]);
  }
  gl_lds16(bbase + soff, smem + doff);                       // plane1 half
  gl_lds16(bbase + 8192 + soff, smem + 4096 + doff);         // plane2 half
  DRAIN_BAR();

  #pragma unroll 1
  for (int kt = 0; kt < NKQ; kt += 2){
    { // even: compute (setA, buf0); prefetch kt+1 -> (setB, buf1)
      const char* bb = bbase + (size_t)(kt + 1) * 16384;
      gl_lds16(bb + soff, smem + 8192 + doff);
      gl_lds16(bb + 8192 + soff, smem + 12288 + doff);
      __builtin_amdgcn_sched_barrier(0);          // pin: B issued before A
      const char* ab = abase + (size_t)(kt + 1) * 16384;
      #pragma unroll
      for (int i = 0; i < 2; ++i){
        a1B[i] = *reinterpret_cast<const i32x4*>(ab + aoffs[i]);
        a2B[i] = *reinterpret_cast<const i32x4*>(ab + 8192 + aoffs[i]);
      }
      const char* SB = smem;
      #pragma unroll
      for (int j = 0; j < 4; ++j){
        i32x4 b1 = *reinterpret_cast<const i32x4*>(SB + boffs[j]);
        i32x4 b2 = *reinterpret_cast<const i32x4*>(SB + 4096 + boffs[j]);
        #pragma unroll
        for (int i = 0; i < 2; ++i){
          accm[i][j] = MFMAI(a1A[i], b1, accm[i][j]);
          accc[i][j] = MFMAI(a1A[i], b2, accc[i][j]);
          accc[i][j] = MFMAI(a2A[i], b1, accc[i][j]);
        }
      }
      CNT_BAR4();   // B(kt+1) landed; A(kt+1) still in flight (waited at use)
    }
    { // odd: compute (setB, buf1); prefetch kt+2 -> (setA, buf0)
      if (kt + 2 < NKQ){
        const char* bb = bbase + (size_t)(kt + 2) * 16384;
        gl_lds16(bb + soff, smem + doff);
        gl_lds16(bb + 8192 + soff, smem + 4096 + doff);
        __builtin_amdgcn_sched_barrier(0);        // pin: B issued before A
        const char* ab = abase + (size_t)(kt + 2) * 16384;
        #pragma unroll
        for (int i = 0; i < 2; ++i){
          a1A[i] = *reinterpret_cast<const i32x4*>(ab + aoffs[i]);
          a2A[i] = *reinterpret_cast<const i32x4*>(ab + 8192 + aoffs[i]);
        }
      }
      const char* SB = smem + 8192;
      #pragma unroll
      for (int j = 0; j < 4; ++j){
        i32x4 b1 = *reinterpret_cast<const i32x4*>(SB + boffs[j]);
        i32x4 b2 = *reinterpret_cast<const i32x4*>(SB + 4096 + boffs[j]);
        #pragma unroll
        for (int i = 0; i < 2; ++i){
          accm[i][j] = MFMAI(a1B[i], b1, accm[i][j]);
          accc[i][j] = MFMAI(a1B[i], b2, accc[i][j]);
          accc[i][j] = MFMAI(a2B[i], b1, accc[i][j]);
        }
      }
      CNT_BAR4();
    }
  }

  // epilogue: arg = sX[row]*sW[col]*(main + cross/256) + b[col]
  // row = mb*128 + wid*32 + i*16 + g*4 + p, col = nb2*64 + r*4 + j
  int colb = nb2 * 64 + r * 4;
  f32x4 sw4 = *reinterpret_cast<const f32x4*>(sW + colb);
  f32x4 bv  = *reinterpret_cast<const f32x4*>(bvec + colb);
  #pragma unroll
  for (int i = 0; i < 2; ++i){
    int rowb = mb * 128 + wid * 32 + i * 16 + g * 4;
    f32x4 sx4 = *reinterpret_cast<const f32x4*>(sX + rowb);
    #pragma unroll
    for (int p = 0; p < 4; ++p){
      float sx = sx4[p];
      f32x4 o;
      o.x = cos_scaled(fmaf(sx * sw4.x,
              (float)accm[i][0][p] + (float)accc[i][0][p] * 0.00390625f, bv.x));
      o.y = cos_scaled(fmaf(sx * sw4.y,
              (float)accm[i][1][p] + (float)accc[i][1][p] * 0.00390625f, bv.y));
      o.z = cos_scaled(fmaf(sx * sw4.z,
              (float)accm[i][2][p] + (float)accc[i][2][p] * 0.00390625f, bv.z));
      o.w = cos_scaled(fmaf(sx * sw4.w,
              (float)accm[i][3][p] + (float)accc[i][3][p] * 0.00390625f, bv.w));
      __builtin_nontemporal_store(o,
          reinterpret_cast<f32x4*>(out + (size_t)(rowb + p) * N_COLS + colb));
    }
  }
}

// ================= fallback (no workspace): bf16 3-product ==================
#define MFMA_(a,b,c) __builtin_amdgcn_mfma_f32_16x16x32_bf16(a,b,c,0,0,0)
constexpr int LDSK = 40;
constexpr int SEC  = 128 * LDSK;
__launch_bounds__(256, 2)
__global__ void rbf_gemm_nows(const float* __restrict__ X, const float* __restrict__ W,
                              const float* __restrict__ bvec, float* __restrict__ out){
  __shared__ __align__(16) unsigned short smem[4 * SEC];
  int orig = blockIdx.x;
  int wgid = (orig & 7) * (int)(gridDim.x >> 3) + (orig >> 3);
  int mb = wgid >> 4, nb = wgid & 15;
  int m0 = mb * 128, n0 = nb * 128;
  int tid = threadIdx.x, lane = tid & 63, wid = tid >> 6;
  int wm = wid >> 1, wn = wid & 1;
  int r = lane & 15, g = lane >> 4;

  const float* asrc[4]; int alofs[4]; float4 ra[4];
  const float* wsrc[4]; int wnq4[4]; int wkr[4]; float4 rw[4];
  #pragma unroll
  for (int i = 0; i < 4; ++i){
    int c = tid + i * 256;
    int row = c >> 3, q = c & 7;
    asrc[i]  = X + (size_t)(m0 + row) * K_DIM + q * 4;
    alofs[i] = row * LDSK + q * 4;
  }
  #pragma unroll
  for (int i = 0; i < 4; ++i) ra[i] = *reinterpret_cast<const float4*>(asrc[i]);
  #pragma unroll
  for (int i = 0; i < 4; ++i){
    int c = tid + i * 256;
    int kr = c >> 5, nq = c & 31;
    wsrc[i] = W + (size_t)kr * N_COLS + n0 + nq * 4;
    wkr[i] = kr; wnq4[i] = nq * 4;
  }
  #pragma unroll
  for (int i = 0; i < 4; ++i) rw[i] = *reinterpret_cast<const float4*>(wsrc[i]);

  f32x4 acc[4][4];
  #pragma unroll
  for (int i = 0; i < 4; ++i)
    #pragma unroll
    for (int j = 0; j < 4; ++j) acc[i][j] = (f32x4){0.f,0.f,0.f,0.f};

  int aoff[4], boff[4];
  #pragma unroll
  for (int i = 0; i < 4; ++i) aoff[i] = (wm*64 + i*16 + r) * LDSK + g * 8;
  #pragma unroll
  for (int j = 0; j < 4; ++j) boff[j] = (wn*64 + j*16 + r) * LDSK + g * 8;

  #pragma unroll 1
  for (int kt = 0; kt < 16; ++kt){
    __syncthreads();
    #pragma unroll
    for (int i = 0; i < 4; ++i){
      ushort4 h, l;
      split4(ra[i], h, l);
      *reinterpret_cast<ushort4*>(&smem[alofs[i]])       = h;
      *reinterpret_cast<ushort4*>(&smem[SEC + alofs[i]]) = l;
    }
    #pragma unroll
    for (int i = 0; i < 4; ++i){
      float vv[4] = {rw[i].x, rw[i].y, rw[i].z, rw[i].w};
      #pragma unroll
      for (int w2 = 0; w2 < 4; ++w2){
        unsigned short h = f2bf(vv[w2]);
        unsigned short l = f2bf(vv[w2] - bf2f(h));
        int n = wnq4[i] + w2;
        smem[2*SEC + n*LDSK + wkr[i]] = h;
        smem[3*SEC + n*LDSK + wkr[i]] = l;
      }
    }
    if (kt < 15){
      #pragma unroll
      for (int i = 0; i < 4; ++i)
        ra[i] = *reinterpret_cast<const float4*>(asrc[i] + (kt+1)*32);
      #pragma unroll
      for (int i = 0; i < 4; ++i)
        rw[i] = *reinterpret_cast<const float4*>(wsrc[i] + (size_t)(kt+1)*32*N_COLS);
    }
    __syncthreads();
    bf16x8 ah[4], al[4], bh[4], bl[4];
    #pragma unroll
    for (int i = 0; i < 4; ++i){
      ah[i] = *reinterpret_cast<const bf16x8*>(&smem[aoff[i]]);
      al[i] = *reinterpret_cast<const bf16x8*>(&smem[SEC + aoff[i]]);
    }
    #pragma unroll
    for (int j = 0; j < 4; ++j){
      bh[j] = *reinterpret_cast<const bf16x8*>(&smem[2*SEC + boff[j]]);
      bl[j] = *reinterpret_cast<const bf16x8*>(&smem[3*SEC + boff[j]]);
    }
    #pragma unroll
    for (int i = 0; i < 4; ++i){
      #pragma unroll
      for (int j = 0; j < 4; ++j){
        acc[i][j] = MFMA_(ah[i], bh[j], acc[i][j]);
        acc[i][j] = MFMA_(al[i], bh[j], acc[i][j]);
        acc[i][j] = MFMA_(ah[i], bl[j], acc[i][j]);
      }
    }
  }

  float bvv[4];
  #pragma unroll
  for (int j = 0; j < 4; ++j) bvv[j] = bvec[n0 + wn*64 + j*16 + r];
  #pragma unroll
  for (int i = 0; i < 4; ++i){
    #pragma unroll
    for (int j = 0; j < 4; ++j){
      int col = n0 + wn*64 + j*16 + r;
      #pragma unroll
      for (int p = 0; p < 4; ++p){
        int row = m0 + wm*64 + i*16 + g*4 + p;
        out[(size_t)row * N_COLS + col] = cos_scaled(acc[i][j][p] + bvv[j]);
      }
    }
  }
}

extern "C" void kernel_launch(void* const* d_in, const int* in_sizes, int n_in,
                              void* d_out, int out_size, void* d_ws, size_t ws_size,
                              hipStream_t stream){
  const float* X = (const float*)d_in[0];
  const float* W = (const float*)d_in[1];
  const float* b = (const float*)d_in[2];
  float* out = (float*)d_out;
  char* ws = (char*)d_ws;

  if (ws && ws_size >= NEEDQ){
    float* sX = (float*)ws;
    float* sW = (float*)(ws + 65536 * 4);
    char*  AQ = ws + AQ_OFF;
    char*  WQ = ws + WQ_OFF;
    pack_xq<<<2048, 256, 0, stream>>>(X, AQ, sX);
    prep_w<<<NBQ, 256, 0, stream>>>(W, sW, WQ);
    rbf_gemm_i8<<<16384, 256, 0, stream>>>(AQ, WQ, sX, sW, b, out);
  } else {
    rbf_gemm_nows<<<8192, 256, 0, stream>>>(X, W, b, out);
  }
}

// Round 16
// 311.165 us; speedup vs baseline: 1.1491x; 1.1491x over previous
//
#include <hip/hip_runtime.h>

typedef __bf16 bf16x8 __attribute__((ext_vector_type(8)));
typedef float  f32x4  __attribute__((ext_vector_type(4)));
typedef int    i32x4  __attribute__((ext_vector_type(4)));
typedef char   c16    __attribute__((ext_vector_type(16)));

constexpr int M_ROWS = 65536;
constexpr int N_COLS = 2048;
constexpr int K_DIM  = 512;
constexpr int NKQ    = 8;              // kt-tiles of K=64
constexpr int MBQ    = 512;            // 128-row tiles
constexpr int NBQ    = 16;             // 128-col WQ blocks

// ws layout: sX 65536 f | sW 2048 f | AQ 64 MiB | WQ 2 MiB
constexpr size_t AQ_OFF  = (65536 + 2048) * 4;
constexpr size_t AQ_SZ   = (size_t)MBQ * NKQ * 16384;
constexpr size_t WQ_OFF  = AQ_OFF + AQ_SZ;
constexpr size_t WQ_SZ   = (size_t)NBQ * NKQ * 16384;
constexpr size_t NEEDQ   = WQ_OFF + WQ_SZ;

__device__ __forceinline__ unsigned short f2bf(float f){
  unsigned int u = __float_as_uint(f);
  u += 0x7FFFu + ((u >> 16) & 1u);
  return (unsigned short)(u >> 16);
}
__device__ __forceinline__ float bf2f(unsigned short h){
  return __uint_as_float(((unsigned int)h) << 16);
}
__device__ __forceinline__ void split4(const float4& v, ushort4& h, ushort4& l){
  h.x = f2bf(v.x); l.x = f2bf(v.x - bf2f(h.x));
  h.y = f2bf(v.y); l.y = f2bf(v.y - bf2f(h.y));
  h.z = f2bf(v.z); l.z = f2bf(v.z - bf2f(h.z));
  h.w = f2bf(v.w); l.w = f2bf(v.w - bf2f(h.w));
}

__device__ __forceinline__ void gl_lds16(const void* g, void* l){
  __builtin_amdgcn_global_load_lds(
      (const __attribute__((address_space(1))) unsigned int*)g,
      (__attribute__((address_space(3))) unsigned int*)l, 16, 0, 0);
}

constexpr float INV2PI = 0.15915494309189535f;
__device__ __forceinline__ float cos_scaled(float v){
  float rev = v * INV2PI;
  rev -= floorf(rev);
  return 0.03125f * __builtin_amdgcn_cosf(rev);
}

__device__ __forceinline__ void q2(float x, float inv, char& o1, char& o2){
  float t1 = x * inv;
  float r1 = rintf(t1);
  float r2 = fminf(rintf((t1 - r1) * 256.0f), 127.0f);
  o1 = (char)(int)r1;
  o2 = (char)(int)r2;
}

// ============ prepass 1: X -> AQ (fused rowmax + 2-split i8, frag-linear) ===
__global__ void pack_xq(const float* __restrict__ X, char* __restrict__ AQ,
                        float* __restrict__ sXo){
  const int bid = blockIdx.x;          // 2048 blocks x 32 rows
  const int t = threadIdx.x;
  const int rl = t >> 3, seg = t & 7;  // seg == kt
  const int grow = bid * 32 + rl;
  const float* src = X + (size_t)grow * K_DIM + seg * 64;
  f32x4 v[16];
  #pragma unroll
  for (int i = 0; i < 16; ++i)
    v[i] = __builtin_nontemporal_load(reinterpret_cast<const f32x4*>(src) + i);
  float m = 0.f;
  #pragma unroll
  for (int i = 0; i < 16; ++i)
    m = fmaxf(m, fmaxf(fmaxf(fabsf(v[i].x), fabsf(v[i].y)),
                       fmaxf(fabsf(v[i].z), fabsf(v[i].w))));
  m = fmaxf(m, __shfl_xor(m, 1));
  m = fmaxf(m, __shfl_xor(m, 2));
  m = fmaxf(m, __shfl_xor(m, 4));
  m = fmaxf(m, 1e-10f);
  if (seg == 0) sXo[grow] = m * (1.0f / 127.0f);
  const float inv = 127.0f / m;

  const int mb = bid >> 2;
  const int rowt = (bid & 3) * 32 + rl;
  const int i_ = rowt >> 4, r_ = rowt & 15;
  char* tb = AQ + (size_t)(mb * NKQ + seg) * 16384;
  #pragma unroll
  for (int q = 0; q < 4; ++q){
    c16 o1, o2;
    #pragma unroll
    for (int u = 0; u < 4; ++u){
      f32x4 xv = v[q * 4 + u];
      #pragma unroll
      for (int w = 0; w < 4; ++w){
        char a, b; q2(xv[w], inv, a, b);
        o1[u * 4 + w] = a; o2[u * 4 + w] = b;
      }
    }
    int c = i_ * 64 + q * 16 + r_;
    *reinterpret_cast<c16*>(tb + c * 16)        = o1;
    *reinterpret_cast<c16*>(tb + 8192 + c * 16) = o2;
  }
}

// ============ prepass 2: per-col max of W ===================================
__global__ void scale_w(const float* __restrict__ W, float* __restrict__ sWo){
  __shared__ float red[8][32];
  int t = threadIdx.x, nl = t & 31, kq = t >> 5;
  int n = blockIdx.x * 32 + nl;
  float m = 0.f;
  for (int k = kq * 64; k < kq * 64 + 64; ++k)
    m = fmaxf(m, fabsf(W[(size_t)k * N_COLS + n]));
  red[kq][nl] = m;
  __syncthreads();
  if (kq == 0){
    #pragma unroll
    for (int u = 1; u < 8; ++u) m = fmaxf(m, red[u][nl]);
    sWo[n] = fmaxf(m, 1e-10f) * (1.0f / 127.0f);
  }
}

// ============ prepass 3: W -> WQ (transpose + 2-split i8 + col-perm) ========
__global__ void pack_wq(const float* __restrict__ W, const float* __restrict__ sW,
                        char* __restrict__ WQ){
  __shared__ float tf[64][132];
  const int nb = blockIdx.x, kt = blockIdx.y, t = threadIdx.x;
  const int kr = t >> 2, nq = t & 3;
  #pragma unroll
  for (int it = 0; it < 8; ++it){
    f32x4 v4 = *reinterpret_cast<const f32x4*>(
        W + (size_t)(kt * 64 + kr) * N_COLS + nb * 128 + nq * 32 + it * 4);
    *reinterpret_cast<f32x4*>(&tf[kr][nq * 32 + it * 4]) = v4;
  }
  __syncthreads();
  char* tb = WQ + (size_t)(nb * NKQ + kt) * 16384;
  #pragma unroll
  for (int cc = 0; cc < 2; ++cc){
    int c = t + cc * 256;
    int jj = c >> 6, q = (c >> 4) & 3, fc = c & 15;
    int col_local = (jj >> 2) * 64 + fc * 4 + (jj & 3);
    float inv = 1.0f / sW[nb * 128 + col_local];
    c16 o1, o2;
    #pragma unroll
    for (int e = 0; e < 16; ++e){
      char a, b; q2(tf[q * 16 + e][col_local], inv, a, b);
      o1[e] = a; o2[e] = b;
    }
    *reinterpret_cast<c16*>(tb + c * 16)        = o1;
    *reinterpret_cast<c16*>(tb + 8192 + c * 16) = o2;
  }
}

// ============ main GEMM: 128x64 tiles, counted-vmcnt barrier ================
// r14 structure; ONE change: in-loop barrier waits vmcnt(4) (B's 2 gl_lds
// retired by FIFO; A-loads issued after B float to their use-wait) + raw
// s_barrier instead of __syncthreads' full vmcnt(0) drain.
#define MFMAI(a,b,c) __builtin_amdgcn_mfma_i32_16x16x64_i8(a,b,c,0,0,0)
#define DRAIN_BAR() { asm volatile("s_waitcnt vmcnt(0)" ::: "memory"); \
                      __builtin_amdgcn_sched_barrier(0); __syncthreads(); }
#define CNT_BAR4() { asm volatile("s_waitcnt vmcnt(4)" ::: "memory"); \
                     __builtin_amdgcn_s_barrier(); \
                     __builtin_amdgcn_sched_barrier(0); }

__launch_bounds__(256, 4)
__global__ void rbf_gemm_i8(const char* __restrict__ AQ, const char* __restrict__ WQ,
                            const float* __restrict__ sX, const float* __restrict__ sW,
                            const float* __restrict__ bvec, float* __restrict__ out){
  __shared__ __align__(16) char smem[2 * 8192];   // 16 KB: 2 slots x [p1 4K|p2 4K]

  int orig = blockIdx.x;                          // 16384, % 8 == 0
  int wgid = (orig & 7) * 2048 + (orig >> 3);     // bijective XCD swizzle;
  int mb = wgid >> 5, nb2 = wgid & 31;            // 32 consecutive share one AQ tile
  int nb = nb2 >> 1, wn2 = nb2 & 1;

  int tid = threadIdx.x, lane = tid & 63, wid = tid >> 6;  // wave = 32-row group
  int r = lane & 15, g = lane >> 4;

  const char* abase = AQ + (size_t)mb * NKQ * 16384;
  const char* bbase = WQ + ((size_t)nb * NKQ) * 16384 + wn2 * 4096;
  const int soff = wid * 1024 + lane * 16;        // per-lane global src offset
  const int doff = wid * 1024;                    // WAVE-UNIFORM LDS dest offset

  int aoffs[2];
  #pragma unroll
  for (int i = 0; i < 2; ++i) aoffs[i] = (wid * 2 + i) * 1024 + lane * 16;
  int boffs[4];
  #pragma unroll
  for (int j = 0; j < 4; ++j) boffs[j] = j * 1024 + lane * 16;

  i32x4 accm[2][4], accc[2][4];
  #pragma unroll
  for (int i = 0; i < 2; ++i)
    #pragma unroll
    for (int j = 0; j < 4; ++j){
      accm[i][j] = (i32x4){0,0,0,0};
      accc[i][j] = (i32x4){0,0,0,0};
    }

  i32x4 a1A[2], a2A[2], a1B[2], a2B[2];

  // prologue: A[0] -> set A, B[0] halves -> buf0 (full drain once)
  #pragma unroll
  for (int i = 0; i < 2; ++i){
    a1A[i] = *reinterpret_cast<const i32x4*>(abase + aoffs[i]);
    a2A[i] = *reinterpret_cast<const i32x4*>(abase + 8192 + aoffs[i]);
  }
  gl_lds16(bbase + soff, smem + doff);                       // plane1 half
  gl_lds16(bbase + 8192 + soff, smem + 4096 + doff);         // plane2 half
  DRAIN_BAR();

  #pragma unroll 1
  for (int kt = 0; kt < NKQ; kt += 2){
    { // even: compute (setA, buf0); prefetch kt+1 -> (setB, buf1)
      const char* bb = bbase + (size_t)(kt + 1) * 16384;
      gl_lds16(bb + soff, smem + 8192 + doff);
      gl_lds16(bb + 8192 + soff, smem + 12288 + doff);
      __builtin_amdgcn_sched_barrier(0);          // pin: B issued before A
      const char* ab = abase + (size_t)(kt + 1) * 16384;
      #pragma unroll
      for (int i = 0; i < 2; ++i){
        a1B[i] = *reinterpret_cast<const i32x4*>(ab + aoffs[i]);
        a2B[i] = *reinterpret_cast<const i32x4*>(ab + 8192 + aoffs[i]);
      }
      const char* SB = smem;
      #pragma unroll
      for (int j = 0; j < 4; ++j){
        i32x4 b1 = *reinterpret_cast<const i32x4*>(SB + boffs[j]);
        i32x4 b2 = *reinterpret_cast<const i32x4*>(SB + 4096 + boffs[j]);
        #pragma unroll
        for (int i = 0; i < 2; ++i){
          accm[i][j] = MFMAI(a1A[i], b1, accm[i][j]);
          accc[i][j] = MFMAI(a1A[i], b2, accc[i][j]);
          accc[i][j] = MFMAI(a2A[i], b1, accc[i][j]);
        }
      }
      CNT_BAR4();   // B(kt+1) landed (FIFO); A(kt+1) waits at its use
    }
    { // odd: compute (setB, buf1); prefetch kt+2 -> (setA, buf0)
      if (kt + 2 < NKQ){
        const char* bb = bbase + (size_t)(kt + 2) * 16384;
        gl_lds16(bb + soff, smem + doff);
        gl_lds16(bb + 8192 + soff, smem + 4096 + doff);
        __builtin_amdgcn_sched_barrier(0);        // pin: B issued before A
        const char* ab = abase + (size_t)(kt + 2) * 16384;
        #pragma unroll
        for (int i = 0; i < 2; ++i){
          a1A[i] = *reinterpret_cast<const i32x4*>(ab + aoffs[i]);
          a2A[i] = *reinterpret_cast<const i32x4*>(ab + 8192 + aoffs[i]);
        }
      }
      const char* SB = smem + 8192;
      #pragma unroll
      for (int j = 0; j < 4; ++j){
        i32x4 b1 = *reinterpret_cast<const i32x4*>(SB + boffs[j]);
        i32x4 b2 = *reinterpret_cast<const i32x4*>(SB + 4096 + boffs[j]);
        #pragma unroll
        for (int i = 0; i < 2; ++i){
          accm[i][j] = MFMAI(a1B[i], b1, accm[i][j]);
          accc[i][j] = MFMAI(a1B[i], b2, accc[i][j]);
          accc[i][j] = MFMAI(a2B[i], b1, accc[i][j]);
        }
      }
      CNT_BAR4();
    }
  }

  // epilogue: arg = sX[row]*sW[col]*(main + cross/256) + b[col]
  // row = mb*128 + wid*32 + i*16 + g*4 + p, col = nb2*64 + r*4 + j
  int colb = nb2 * 64 + r * 4;
  f32x4 sw4 = *reinterpret_cast<const f32x4*>(sW + colb);
  f32x4 bv  = *reinterpret_cast<const f32x4*>(bvec + colb);
  #pragma unroll
  for (int i = 0; i < 2; ++i){
    int rowb = mb * 128 + wid * 32 + i * 16 + g * 4;
    f32x4 sx4 = *reinterpret_cast<const f32x4*>(sX + rowb);
    #pragma unroll
    for (int p = 0; p < 4; ++p){
      float sx = sx4[p];
      f32x4 o;
      o.x = cos_scaled(fmaf(sx * sw4.x,
              (float)accm[i][0][p] + (float)accc[i][0][p] * 0.00390625f, bv.x));
      o.y = cos_scaled(fmaf(sx * sw4.y,
              (float)accm[i][1][p] + (float)accc[i][1][p] * 0.00390625f, bv.y));
      o.z = cos_scaled(fmaf(sx * sw4.z,
              (float)accm[i][2][p] + (float)accc[i][2][p] * 0.00390625f, bv.z));
      o.w = cos_scaled(fmaf(sx * sw4.w,
              (float)accm[i][3][p] + (float)accc[i][3][p] * 0.00390625f, bv.w));
      __builtin_nontemporal_store(o,
          reinterpret_cast<f32x4*>(out + (size_t)(rowb + p) * N_COLS + colb));
    }
  }
}

// ================= fallback (no workspace): bf16 3-product ==================
#define MFMA_(a,b,c) __builtin_amdgcn_mfma_f32_16x16x32_bf16(a,b,c,0,0,0)
constexpr int LDSK = 40;
constexpr int SEC  = 128 * LDSK;
__launch_bounds__(256, 2)
__global__ void rbf_gemm_nows(const float* __restrict__ X, const float* __restrict__ W,
                              const float* __restrict__ bvec, float* __restrict__ out){
  __shared__ __align__(16) unsigned short smem[4 * SEC];
  int orig = blockIdx.x;
  int wgid = (orig & 7) * (int)(gridDim.x >> 3) + (orig >> 3);
  int mb = wgid >> 4, nb = wgid & 15;
  int m0 = mb * 128, n0 = nb * 128;
  int tid = threadIdx.x, lane = tid & 63, wid = tid >> 6;
  int wm = wid >> 1, wn = wid & 1;
  int r = lane & 15, g = lane >> 4;

  const float* asrc[4]; int alofs[4]; float4 ra[4];
  const float* wsrc[4]; int wnq4[4]; int wkr[4]; float4 rw[4];
  #pragma unroll
  for (int i = 0; i < 4; ++i){
    int c = tid + i * 256;
    int row = c >> 3, q = c & 7;
    asrc[i]  = X + (size_t)(m0 + row) * K_DIM + q * 4;
    alofs[i] = row * LDSK + q * 4;
  }
  #pragma unroll
  for (int i = 0; i < 4; ++i) ra[i] = *reinterpret_cast<const float4*>(asrc[i]);
  #pragma unroll
  for (int i = 0; i < 4; ++i){
    int c = tid + i * 256;
    int kr = c >> 5, nq = c & 31;
    wsrc[i] = W + (size_t)kr * N_COLS + n0 + nq * 4;
    wkr[i] = kr; wnq4[i] = nq * 4;
  }
  #pragma unroll
  for (int i = 0; i < 4; ++i) rw[i] = *reinterpret_cast<const float4*>(wsrc[i]);

  f32x4 acc[4][4];
  #pragma unroll
  for (int i = 0; i < 4; ++i)
    #pragma unroll
    for (int j = 0; j < 4; ++j) acc[i][j] = (f32x4){0.f,0.f,0.f,0.f};

  int aoff[4], boff[4];
  #pragma unroll
  for (int i = 0; i < 4; ++i) aoff[i] = (wm*64 + i*16 + r) * LDSK + g * 8;
  #pragma unroll
  for (int j = 0; j < 4; ++j) boff[j] = (wn*64 + j*16 + r) * LDSK + g * 8;

  #pragma unroll 1
  for (int kt = 0; kt < 16; ++kt){
    __syncthreads();
    #pragma unroll
    for (int i = 0; i < 4; ++i){
      ushort4 h, l;
      split4(ra[i], h, l);
      *reinterpret_cast<ushort4*>(&smem[alofs[i]])       = h;
      *reinterpret_cast<ushort4*>(&smem[SEC + alofs[i]]) = l;
    }
    #pragma unroll
    for (int i = 0; i < 4; ++i){
      float vv[4] = {rw[i].x, rw[i].y, rw[i].z, rw[i].w};
      #pragma unroll
      for (int w2 = 0; w2 < 4; ++w2){
        unsigned short h = f2bf(vv[w2]);
        unsigned short l = f2bf(vv[w2] - bf2f(h));
        int n = wnq4[i] + w2;
        smem[2*SEC + n*LDSK + wkr[i]] = h;
        smem[3*SEC + n*LDSK + wkr[i]] = l;
      }
    }
    if (kt < 15){
      #pragma unroll
      for (int i = 0; i < 4; ++i)
        ra[i] = *reinterpret_cast<const float4*>(asrc[i] + (kt+1)*32);
      #pragma unroll
      for (int i = 0; i < 4; ++i)
        rw[i] = *reinterpret_cast<const float4*>(wsrc[i] + (size_t)(kt+1)*32*N_COLS);
    }
    __syncthreads();
    bf16x8 ah[4], al[4], bh[4], bl[4];
    #pragma unroll
    for (int i = 0; i < 4; ++i){
      ah[i] = *reinterpret_cast<const bf16x8*>(&smem[aoff[i]]);
      al[i] = *reinterpret_cast<const bf16x8*>(&smem[SEC + aoff[i]]);
    }
    #pragma unroll
    for (int j = 0; j < 4; ++j){
      bh[j] = *reinterpret_cast<const bf16x8*>(&smem[2*SEC + boff[j]]);
      bl[j] = *reinterpret_cast<const bf16x8*>(&smem[3*SEC + boff[j]]);
    }
    #pragma unroll
    for (int i = 0; i < 4; ++i){
      #pragma unroll
      for (int j = 0; j < 4; ++j){
        acc[i][j] = MFMA_(ah[i], bh[j], acc[i][j]);
        acc[i][j] = MFMA_(al[i], bh[j], acc[i][j]);
        acc[i][j] = MFMA_(ah[i], bl[j], acc[i][j]);
      }
    }
  }

  float bvv[4];
  #pragma unroll
  for (int j = 0; j < 4; ++j) bvv[j] = bvec[n0 + wn*64 + j*16 + r];
  #pragma unroll
  for (int i = 0; i < 4; ++i){
    #pragma unroll
    for (int j = 0; j < 4; ++j){
      int col = n0 + wn*64 + j*16 + r;
      #pragma unroll
      for (int p = 0; p < 4; ++p){
        int row = m0 + wm*64 + i*16 + g*4 + p;
        out[(size_t)row * N_COLS + col] = cos_scaled(acc[i][j][p] + bvv[j]);
      }
    }
  }
}

extern "C" void kernel_launch(void* const* d_in, const int* in_sizes, int n_in,
                              void* d_out, int out_size, void* d_ws, size_t ws_size,
                              hipStream_t stream){
  const float* X = (const float*)d_in[0];
  const float* W = (const float*)d_in[1];
  const float* b = (const float*)d_in[2];
  float* out = (float*)d_out;
  char* ws = (char*)d_ws;

  if (ws && ws_size >= NEEDQ){
    float* sX = (float*)ws;
    float* sW = (float*)(ws + 65536 * 4);
    char*  AQ = ws + AQ_OFF;
    char*  WQ = ws + WQ_OFF;
    pack_xq<<<2048, 256, 0, stream>>>(X, AQ, sX);
    scale_w<<<64, 256, 0, stream>>>(W, sW);
    pack_wq<<<dim3(NBQ, NKQ), 256, 0, stream>>>(W, sW, WQ);
    rbf_gemm_i8<<<16384, 256, 0, stream>>>(AQ, WQ, sX, sW, b, out);
  } else {
    rbf_gemm_nows<<<8192, 256, 0, stream>>>(X, W, b, out);
  }
}